// Round 6
// baseline (95.802 us; speedup 1.0000x reference)
//
#include <hip/hip_runtime.h>

// EmbeddingBagCollection: 4 tables, W[1M,64] fp32, mean-pool over jagged bags.
// block = bag, wave = table, lane = 16*g + s (g=row group, s=float4 slot).
// VGPR-diet variant: gather window t[8] (32 VGPR) + 2 accumulators so total
// VGPR <= 64 -> 8 waves/SIMD (32 waves/CU), double R3/R5's residency.
// Per 64-index chunk: two half-chunks of 8 branch-free float4 gathers each.

#define NBAGS 8192
#define DIM 64

__global__ __launch_bounds__(256, 8) void ebc_kernel(
    const float* __restrict__ W0, const int* __restrict__ v0, const int* __restrict__ o0,
    const float* __restrict__ W1, const int* __restrict__ v1, const int* __restrict__ o1,
    const float* __restrict__ W2, const int* __restrict__ v2, const int* __restrict__ o2,
    const float* __restrict__ W3, const int* __restrict__ v3, const int* __restrict__ o3,
    float* __restrict__ out)
{
    const int table = threadIdx.x >> 6;   // wave id within block = table id
    const int lane  = threadIdx.x & 63;
    const int g     = lane >> 4;          // row group 0..3
    const int s     = lane & 15;          // float4 slot within row
    const int bag   = blockIdx.x;

    const float* W; const int* vals; const int* offs;
    if      (table == 0) { W = W0; vals = v0; offs = o0; }
    else if (table == 1) { W = W1; vals = v1; offs = o1; }
    else if (table == 2) { W = W2; vals = v2; offs = o2; }
    else                 { W = W3; vals = v3; offs = o3; }

    const int start = offs[bag];
    const int end   = offs[bag + 1];

    float4 acc0 = {0,0,0,0}, acc1 = {0,0,0,0};

    for (int base = start; base < end; base += 64) {
        const int rem = end - base;
        const int n   = rem < 64 ? rem : 64;
        const int nm1 = n > 0 ? n - 1 : 0;

        int v = 0;
        if (lane < n) v = vals[base + lane];   // one coalesced index load per chunk

        #pragma unroll
        for (int h = 0; h < 2; ++h) {
            const int rb = 32 * h;
            if (rb >= n) break;
            float4 t[8];
            #pragma unroll
            for (int k = 0; k < 8; ++k) {
                const int r   = rb + 4 * k + g;
                const int src = r < nm1 ? r : nm1;     // clamp: valid lane always
                const int idx = __shfl(v, src);
                t[k] = *(const float4*)(W + (size_t)idx * DIM + s * 4);
            }
            #pragma unroll
            for (int k = 0; k < 8; ++k) {
                const float wk = (rb + 4 * k + g < n) ? 1.0f : 0.0f;
                float4* a = (k & 1) ? &acc1 : &acc0;
                a->x = fmaf(t[k].x, wk, a->x);
                a->y = fmaf(t[k].y, wk, a->y);
                a->z = fmaf(t[k].z, wk, a->z);
                a->w = fmaf(t[k].w, wk, a->w);
            }
        }
    }

    float4 acc;
    acc.x = acc0.x + acc1.x;
    acc.y = acc0.y + acc1.y;
    acc.z = acc0.z + acc1.z;
    acc.w = acc0.w + acc1.w;

    acc.x += __shfl_xor(acc.x, 16); acc.y += __shfl_xor(acc.y, 16);
    acc.z += __shfl_xor(acc.z, 16); acc.w += __shfl_xor(acc.w, 16);
    acc.x += __shfl_xor(acc.x, 32); acc.y += __shfl_xor(acc.y, 32);
    acc.z += __shfl_xor(acc.z, 32); acc.w += __shfl_xor(acc.w, 32);

    const int cnt = end - start;
    const float inv = cnt > 0 ? 1.0f / (float)cnt : 0.0f;  // empty bag -> zeros

    if (g == 0) {
        float4 r;
        r.x = acc.x * inv; r.y = acc.y * inv; r.z = acc.z * inv; r.w = acc.w * inv;
        *(float4*)(out + (size_t)bag * (4 * DIM) + table * DIM + s * 4) = r;
    }
}

extern "C" void kernel_launch(void* const* d_in, const int* in_sizes, int n_in,
                              void* d_out, int out_size, void* d_ws, size_t ws_size,
                              hipStream_t stream) {
    const float* W0 = (const float*)d_in[0];
    const int*   v0 = (const int*)  d_in[1];
    const int*   o0 = (const int*)  d_in[2];
    const float* W1 = (const float*)d_in[3];
    const int*   v1 = (const int*)  d_in[4];
    const int*   o1 = (const int*)  d_in[5];
    const float* W2 = (const float*)d_in[6];
    const int*   v2 = (const int*)  d_in[7];
    const int*   o2 = (const int*)  d_in[8];
    const float* W3 = (const float*)d_in[9];
    const int*   v3 = (const int*)  d_in[10];
    const int*   o3 = (const int*)  d_in[11];
    float* out = (float*)d_out;

    ebc_kernel<<<NBAGS, 256, 0, stream>>>(W0, v0, o0, W1, v1, o1,
                                          W2, v2, o2, W3, v3, o3, out);
}

// Round 7
// 76.583 us; speedup vs baseline: 1.2510x; 1.2510x over previous
//
#include <hip/hip_runtime.h>

// EmbeddingBagCollection: 4 tables, W[1M,64] fp32, mean-pool over jagged bags.
// block = bag, wave = table, lane = 16*g + s (g=row group, s=float4 slot).
// Per 64-index chunk: 16 branch-free float4 gathers (rows r=4k+g, clamped) are
// issued back-to-back -> 16 KB in flight per wave; contributions weighted by
// (r < n) so clamped duplicates add zero. Epilogue: shfl_xor butterfly over g.
// Best-measured config (R3: 76.9us). R4 (NB=8), R5 (NB=2 pipeline), R6 (VGPR
// diet -> scratch demotion) all matched or regressed: per-CU gather
// concurrency is saturated; HBM fetch (210 MB) is cache-optimal.

#define NBAGS 8192
#define DIM 64

__global__ __launch_bounds__(256) void ebc_kernel(
    const float* __restrict__ W0, const int* __restrict__ v0, const int* __restrict__ o0,
    const float* __restrict__ W1, const int* __restrict__ v1, const int* __restrict__ o1,
    const float* __restrict__ W2, const int* __restrict__ v2, const int* __restrict__ o2,
    const float* __restrict__ W3, const int* __restrict__ v3, const int* __restrict__ o3,
    float* __restrict__ out)
{
    const int table = threadIdx.x >> 6;   // wave id within block = table id
    const int lane  = threadIdx.x & 63;
    const int g     = lane >> 4;          // row group 0..3
    const int s     = lane & 15;          // float4 slot within row
    const int bag   = blockIdx.x;

    const float* W; const int* vals; const int* offs;
    if      (table == 0) { W = W0; vals = v0; offs = o0; }
    else if (table == 1) { W = W1; vals = v1; offs = o1; }
    else if (table == 2) { W = W2; vals = v2; offs = o2; }
    else                 { W = W3; vals = v3; offs = o3; }

    const int start = offs[bag];
    const int end   = offs[bag + 1];

    float4 acc0 = {0,0,0,0}, acc1 = {0,0,0,0}, acc2 = {0,0,0,0}, acc3 = {0,0,0,0};

    for (int base = start; base < end; base += 64) {
        const int rem = end - base;
        const int n   = rem < 64 ? rem : 64;
        const int nm1 = n - 1;

        int v = 0;
        if (lane < n) v = vals[base + lane];   // one coalesced index load per chunk

        float4 t[16];
        float  w[16];
        #pragma unroll
        for (int k = 0; k < 16; ++k) {
            const int r   = 4 * k + g;
            const int src = r < nm1 ? r : nm1;        // clamp: always a valid lane
            const int idx = __shfl(v, src);           // bpermute broadcast
            t[k] = *(const float4*)(W + (size_t)idx * DIM + s * 4);
            w[k] = (r < n) ? 1.0f : 0.0f;
        }
        #pragma unroll
        for (int k = 0; k < 16; ++k) {
            float4* a = (k & 3) == 0 ? &acc0 : (k & 3) == 1 ? &acc1
                       : (k & 3) == 2 ? &acc2 : &acc3;
            a->x = fmaf(t[k].x, w[k], a->x);
            a->y = fmaf(t[k].y, w[k], a->y);
            a->z = fmaf(t[k].z, w[k], a->z);
            a->w = fmaf(t[k].w, w[k], a->w);
        }
    }

    float4 acc;
    acc.x = (acc0.x + acc1.x) + (acc2.x + acc3.x);
    acc.y = (acc0.y + acc1.y) + (acc2.y + acc3.y);
    acc.z = (acc0.z + acc1.z) + (acc2.z + acc3.z);
    acc.w = (acc0.w + acc1.w) + (acc2.w + acc3.w);

    acc.x += __shfl_xor(acc.x, 16); acc.y += __shfl_xor(acc.y, 16);
    acc.z += __shfl_xor(acc.z, 16); acc.w += __shfl_xor(acc.w, 16);
    acc.x += __shfl_xor(acc.x, 32); acc.y += __shfl_xor(acc.y, 32);
    acc.z += __shfl_xor(acc.z, 32); acc.w += __shfl_xor(acc.w, 32);

    const int cnt = end - start;
    const float inv = cnt > 0 ? 1.0f / (float)cnt : 0.0f;  // empty bag -> zeros

    if (g == 0) {
        float4 r;
        r.x = acc.x * inv; r.y = acc.y * inv; r.z = acc.z * inv; r.w = acc.w * inv;
        *(float4*)(out + (size_t)bag * (4 * DIM) + table * DIM + s * 4) = r;
    }
}

extern "C" void kernel_launch(void* const* d_in, const int* in_sizes, int n_in,
                              void* d_out, int out_size, void* d_ws, size_t ws_size,
                              hipStream_t stream) {
    const float* W0 = (const float*)d_in[0];
    const int*   v0 = (const int*)  d_in[1];
    const int*   o0 = (const int*)  d_in[2];
    const float* W1 = (const float*)d_in[3];
    const int*   v1 = (const int*)  d_in[4];
    const int*   o1 = (const int*)  d_in[5];
    const float* W2 = (const float*)d_in[6];
    const int*   v2 = (const int*)  d_in[7];
    const int*   o2 = (const int*)  d_in[8];
    const float* W3 = (const float*)d_in[9];
    const int*   v3 = (const int*)  d_in[10];
    const int*   o3 = (const int*)  d_in[11];
    float* out = (float*)d_out;

    ebc_kernel<<<NBAGS, 256, 0, stream>>>(W0, v0, o0, W1, v1, o1,
                                          W2, v2, o2, W3, v3, o3, out);
}